// Round 5
// baseline (438.539 us; speedup 1.0000x reference)
//
#include <hip/hip_runtime.h>
#include <hip/hip_bf16.h>

#define DEVI __device__ __forceinline__

static constexpr int cB = 4, cC = 64, cH = 384, cW = 384;
static constexpr int cHW = cH * cW;           // 147456
static constexpr int cP  = 2048;              // MAX_POS
static constexpr int cKC = 20480;             // candidate pool
static constexpr int cKN = 10240;             // max negatives
static constexpr int cNT = cP + cKN;          // 12288 logical cols in loss GEMM
static constexpr float cTEMP_INV = 10.0f;     // 1/TEMP
static constexpr int cCHUNK = 2048;           // elems per selection block
static constexpr int cNB = cHW / cCHUNK;      // 72 selection blocks per image
static constexpr int cNCH = 8;                // column chunks for k_loss
static constexpr int cTPC = (cNT / 16) / cNCH; // 96 col tiles per chunk
static constexpr int cMTW = 10;               // col tiles per wave in k_mine
static constexpr int cMCW = 160;              // cols per wave in k_mine
static constexpr int cMCB = 640;              // cols per block in k_mine
static constexpr int cLOSS_BLOCKS = (cP / 64) * cNCH * cB;  // 1024

using f32x4  = __attribute__((ext_vector_type(4))) float;
using bf16x8 = __attribute__((ext_vector_type(8))) __bf16;

// ---- workspace layout (bytes) ----
static constexpr size_t off_fg   = 0;
static constexpr size_t off_tmp  = off_fg   + (size_t)cB * cHW;
static constexpr size_t off_rim  = off_tmp  + (size_t)cB * cHW;
static constexpr size_t off_pidx = off_rim  + (size_t)cB * cHW;
static constexpr size_t off_cidx = off_pidx + (size_t)cB * cP * 4;
static constexpr size_t off_scal = off_cidx + (size_t)cB * cKC * 4;
static constexpr size_t off_EL   = off_scal + 256;
static constexpr size_t off_msim = off_EL   + (size_t)cNCH * cB * cP * 8;
static constexpr size_t off_nsel = off_msim + (size_t)cB * 2 * cKC * 4;
static constexpr size_t off_G    = off_nsel + (size_t)cB * cKN * 4;
static constexpr size_t off_cf   = off_G    + (size_t)cB * cP * cC * 2;
static constexpr size_t off_bcnt = off_cf   + (size_t)cB * cKC * cC * 2;
static constexpr size_t off_boff = off_bcnt + (size_t)cB * cNB * 4;
// total ≈ 15 MB

DEVI f32x4 mfma16(bf16x8 a, bf16x8 b, f32x4 c) {
  return __builtin_amdgcn_mfma_f32_16x16x32_bf16(a, b, c, 0, 0, 0);
}

// ---------------- fused fg + horizontal dilation (bit-window) ----------------
__global__ __launch_bounds__(256) void k_fg_hdil(const int* labels, unsigned char* fg, unsigned char* tmp) {
  int t = blockIdx.x * 256 + threadIdx.x;   // over cB*cHW/8
  int base = t * 8;                          // 8 px per thread, within one row (8 | 384)
  int x0 = base % cW;
  const int* lb = labels + (base - x0);      // row start
  unsigned m = 0;
#pragma unroll
  for (int j = 0; j < 18; j++) {
    int x = x0 - 5 + j;
    int v = (x >= 0 && x < cW) ? (lb[x] > 0) : 0;
    m |= (unsigned)v << j;
  }
  unsigned long long fgb = 0, tmb = 0;
#pragma unroll
  for (int e = 0; e < 8; e++) {
    fgb |= (unsigned long long)((m >> (e + 5)) & 1u) << (8 * e);
    tmb |= (unsigned long long)(((m >> e) & 0x7FFu) ? 1u : 0u) << (8 * e);
  }
  *(unsigned long long*)(fg + base)  = fgb;
  *(unsigned long long*)(tmp + base) = tmb;
}

// vertical dilation + rim + per-block packed counts (fg | rim<<16)
__global__ __launch_bounds__(256) void k_vdil_count(const unsigned char* tmp, const unsigned char* fg,
                                                    unsigned char* rim, int* blkcnt) {
  __shared__ int red[256];
  int b = blockIdx.y, blk = blockIdx.x, tid = threadIdx.x;
  int base = blk * cCHUNK + tid * 8;
  const unsigned char* tb  = tmp + (size_t)b * cHW;
  const unsigned char* fgb = fg  + (size_t)b * cHW;
  unsigned long long fv = *(const unsigned long long*)(fgb + base);
  int y = base / cW, x = base % cW;
  int lo = max(y - 5, 0), hi = min(y + 5, cH - 1);
  unsigned long long m8 = 0;
  for (int yy = lo; yy <= hi; yy++) m8 |= *(const unsigned long long*)(tb + yy * cW + x);
  unsigned long long pk = m8 & (fv ^ 0x0101010101010101ULL);
  *(unsigned long long*)(rim + (size_t)b * cHW + base) = pk;
  int cfg  = __popcll(fv & 0x0101010101010101ULL);
  int crim = __popcll(pk & 0x0101010101010101ULL);
  red[tid] = cfg | (crim << 16);
  __syncthreads();
  for (int s = 128; s > 0; s >>= 1) {
    if (tid < s) red[tid] += red[tid + s];
    __syncthreads();
  }
  if (tid == 0) blkcnt[b * cNB + blk] = red[0];
}

// per-image exclusive scan over the 72 block counts (+ zero the loss completion counter)
__global__ __launch_bounds__(128) void k_offsets(const int* blkcnt, int2* blkoff, int* scal) {
  __shared__ int sf[128], sr[128];
  int b = blockIdx.x, tid = threadIdx.x;
  if (b == 0 && tid == 0) scal[15] = 0;   // completion counter for k_loss
  int v = (tid < cNB) ? blkcnt[b * cNB + tid] : 0;
  int f = v & 0xffff, r = v >> 16;
  sf[tid] = f; sr[tid] = r;
  __syncthreads();
  for (int d = 1; d < 128; d <<= 1) {
    int tf = (tid >= d) ? sf[tid - d] : 0;
    int tr = (tid >= d) ? sr[tid - d] : 0;
    __syncthreads();
    sf[tid] += tf; sr[tid] += tr;
    __syncthreads();
  }
  if (tid < cNB) blkoff[b * cNB + tid] = make_int2(sf[tid] - f, sr[tid] - r);
  if (tid == 0) {
    int nfg = sf[cNB - 1], nrim = sr[cNB - 1];
    scal[b * 16 + 0] = nfg;
    scal[b * 16 + 1] = min(nfg, cP);    // P_valid
    scal[b * 16 + 2] = min(nrim, cKC);  // C_valid
    scal[b * 16 + 4] = nrim;
  }
}

__device__ int scan_excl_256(int v, int* lds) {
  int tid = threadIdx.x;
  lds[tid] = v;
  __syncthreads();
  for (int d = 1; d < 256; d <<= 1) {
    int t = (tid >= d) ? lds[tid - d] : 0;
    __syncthreads();
    lds[tid] += t;
    __syncthreads();
  }
  int e = lds[tid] - v;
  __syncthreads();
  return e;
}

// raster-order scatter: fg->pidx (fill !fg), rim->cidx (fill !rim)
__global__ __launch_bounds__(256) void k_scatter(const unsigned char* fg, const unsigned char* rim,
                                                 const int2* blkoff, const int* scal,
                                                 int* pidx, int* cidx) {
  __shared__ int lds[256];
  int b = blockIdx.y, blk = blockIdx.x, tid = threadIdx.x;
  int2 off = blkoff[b * cNB + blk];
  int nfg  = scal[b * 16 + 0];
  int nrim = scal[b * 16 + 4];
  bool needf = (off.x < cP)  || (nfg  < cP);
  bool needr = (off.y < cKC) || (nrim < cKC);
  if (!needf && !needr) return;
  int base = blk * cCHUNK + tid * 8;
  const unsigned char* fgb  = fg  + (size_t)b * cHW;
  const unsigned char* rimb = rim + (size_t)b * cHW;
  unsigned long long fv = *(const unsigned long long*)(fgb + base);
  unsigned long long rv = *(const unsigned long long*)(rimb + base);
  int cfg  = __popcll(fv & 0x0101010101010101ULL);
  int crim = __popcll(rv & 0x0101010101010101ULL);
  int ex = scan_excl_256(cfg | (crim << 16), lds);
  int of  = off.x + (ex & 0xffff);
  int orr = off.y + (ex >> 16);
  int* pout = pidx + (size_t)b * cP;
  int* cout = cidx + (size_t)b * cKC;
#pragma unroll
  for (int e = 0; e < 8; e++) {
    int p = base + e;
    int f = (int)((fv >> (8 * e)) & 1);
    int r = (int)((rv >> (8 * e)) & 1);
    if (f) { if (of < cP) pout[of] = p; of++; }
    else if (nfg < cP) { int o = nfg + (p - of); if (o < cP) pout[o] = p; }
    if (r) { if (orr < cKC) cout[orr] = p; orr++; }
    else if (nrim < cKC) { int o = nrim + (p - orr); if (o < cKC) cout[o] = p; }
  }
}

// ---------------- gather + L2-normalize -> bf16 rows (both pools, one launch) ----------------
__global__ __launch_bounds__(256) void k_gather_norm(const float* feat, const int* pidx, const int* cidx,
                                                     __hip_bfloat16* G, __hip_bfloat16* cf) {
  int b = blockIdx.y;
  int bx = blockIdx.x;
  int p;
  __hip_bfloat16* out;
  if (bx < cP / 256) {
    int i = bx * 256 + threadIdx.x;
    p = pidx[(size_t)b * cP + i];
    out = G + (size_t)b * cP * cC + (size_t)i * cC;
  } else {
    int i = (bx - cP / 256) * 256 + threadIdx.x;
    p = cidx[(size_t)b * cKC + i];
    out = cf + (size_t)b * cKC * cC + (size_t)i * cC;
  }
  const float* fb = feat + (size_t)b * cC * cHW + p;
  float v[cC];
  float ss = 0.f;
#pragma unroll
  for (int c = 0; c < cC; c++) { float t = fb[(size_t)c * cHW]; v[c] = t; ss += t * t; }
  float sc = 1.0f / fmaxf(sqrtf(ss), 1e-8f);
#pragma unroll
  for (int c = 0; c < cC; c++) out[c] = __float2bfloat16(v[c] * sc);
}

// ---------------- hard-negative mining: column max of pf @ cf^T ----------------
// 160 cols/wave, 640/block; A chunk LDS-staged in two 64KB halves (XOR-swizzled)
__global__ __launch_bounds__(256) void k_mine(const __hip_bfloat16* G, const __hip_bfloat16* cf,
                                              const int* scal, float* msim) {
  __shared__ int4 smem[4096];           // 64 KB: 512 rows x 8 x 16B, swizzled
  int b = blockIdx.z, rc = blockIdx.y;
  int P_valid = scal[b * 16 + 1];
  int wave = threadIdx.x >> 6, lane = threadIdx.x & 63;
  int lr = lane & 15, quad = lane >> 4;
  int colbase = blockIdx.x * cMCB + wave * cMCW;
  float* msout = msim + ((size_t)b * 2 + rc) * cKC;
  int chunk_lo = rc * 1024;
  if (chunk_lo >= P_valid) {
    if (quad == 0) {
#pragma unroll
      for (int tt = 0; tt < cMTW; tt++) msout[colbase + tt * 16 + lr] = -INFINITY;
    }
    return;
  }
  const int4* pf4 = (const int4*)((const __bf16*)(G + (size_t)b * cP * cC)) + (size_t)chunk_lo * 8;
  const __bf16* cfb = (const __bf16*)(cf + (size_t)b * cKC * cC);

  bf16x8 bfr[cMTW][2];
#pragma unroll
  for (int tt = 0; tt < cMTW; tt++) {
    const __bf16* src = cfb + (size_t)(colbase + tt * 16 + lr) * cC + quad * 8;
    bfr[tt][0] = *(const bf16x8*)src;
    bfr[tt][1] = *(const bf16x8*)(src + 32);
  }
  float cmax[cMTW];
#pragma unroll
  for (int tt = 0; tt < cMTW; tt++) cmax[tt] = -INFINITY;

  int swz  = quad ^ (lr & 7);
  int swz2 = (quad + 4) ^ (lr & 7);
  for (int half = 0; half < 2; half++) {
    for (int i = threadIdx.x; i < 4096; i += 256) {
      int r = i >> 3, q = i & 7;
      smem[r * 8 + (q ^ (r & 7))] = pf4[(size_t)(half * 512 + r) * 8 + q];
    }
    __syncthreads();
    int rowg0 = chunk_lo + half * 512;
    bool full = (rowg0 + 512) <= P_valid;
    for (int mtl = 0; mtl < 32; mtl++) {
      int rl = mtl * 16 + lr;
      bf16x8 a0 = *(bf16x8*)&smem[rl * 8 + swz];
      bf16x8 a1 = *(bf16x8*)&smem[rl * 8 + swz2];
      int rb = rowg0 + mtl * 16 + quad * 4;
#pragma unroll
      for (int tt = 0; tt < cMTW; tt++) {
        f32x4 acc = {0, 0, 0, 0};
        acc = mfma16(a0, bfr[tt][0], acc);
        acc = mfma16(a1, bfr[tt][1], acc);
        if (full) {
          cmax[tt] = fmaxf(cmax[tt], fmaxf(fmaxf(acc[0], acc[1]), fmaxf(acc[2], acc[3])));
        } else {
#pragma unroll
          for (int r = 0; r < 4; r++)
            cmax[tt] = fmaxf(cmax[tt], (rb + r) < P_valid ? acc[r] : -INFINITY);
        }
      }
    }
    __syncthreads();
  }
#pragma unroll
  for (int tt = 0; tt < cMTW; tt++) {
    float c = cmax[tt];
    c = fmaxf(c, __shfl_xor(c, 16));
    c = fmaxf(c, __shfl_xor(c, 32));
    if (quad == 0) msout[colbase + tt * 16 + lr] = c;
  }
}

// ---------------- top-KEEP selection (radix threshold; register-resident keys) ----------------
DEVI unsigned f2key(float f) {
  unsigned u = __float_as_uint(f);
  return (u & 0x80000000u) ? ~u : (u | 0x80000000u);
}

__device__ int scan_excl_1024(int v, int* lds, int* total) {
  int tid = threadIdx.x;
  lds[tid] = v;
  __syncthreads();
  for (int d = 1; d < 1024; d <<= 1) {
    int t = (tid >= d) ? lds[tid - d] : 0;
    __syncthreads();
    lds[tid] += t;
    __syncthreads();
  }
  *total = lds[1023];
  int e = lds[tid] - v;
  __syncthreads();
  return e;
}

__global__ __launch_bounds__(1024) void k_selneg(const float* msim, int* nsel, int* scal) {
  __shared__ int hist[256];
  __shared__ int suf[256];
  __shared__ int lds[1024];
  __shared__ unsigned sh_prefix;
  __shared__ int sh_rem;
  int b = blockIdx.x, tid = threadIdx.x;
  const float* ms0 = msim + ((size_t)b * 2 + 0) * cKC;
  const float* ms1 = msim + ((size_t)b * 2 + 1) * cKC;
  int P_valid = scal[b * 16 + 1], C_valid = scal[b * 16 + 2];
  int n_allowed = min(5 * P_valid, cKN);
  int nfin = (P_valid > 0) ? C_valid : 0;
  int KEEP = min(n_allowed, nfin);
  if (tid == 0) scal[b * 16 + 3] = KEEP;
  if (KEEP == 0) return;

  const int CH2 = cKC / 1024;  // 20
  int base = tid * CH2;
  unsigned keys[CH2];
#pragma unroll
  for (int e = 0; e < CH2; e++) {
    int c = base + e;
    keys[e] = (c < C_valid) ? f2key(fmaxf(ms0[c], ms1[c])) : 0u;
  }

  unsigned prefix = 0;
  int remaining = KEEP;
  for (int shift = 24; shift >= 0; shift -= 8) {
    if (tid < 256) hist[tid] = 0;
    __syncthreads();
#pragma unroll
    for (int e = 0; e < CH2; e++) {
      unsigned key = keys[e];
      if (shift == 24 || (key >> (shift + 8)) == prefix)
        atomicAdd(&hist[(key >> shift) & 255], 1);
    }
    __syncthreads();
    if (tid < 256) suf[tid] = hist[tid];
    __syncthreads();
    for (int d = 1; d < 256; d <<= 1) {
      int t = (tid < 256 && tid + d < 256) ? suf[tid + d] : 0;
      __syncthreads();
      if (tid < 256) suf[tid] += t;
      __syncthreads();
    }
    if (tid < 256) {
      int s = suf[tid];
      int sn = (tid < 255) ? suf[tid + 1] : 0;
      if (s >= remaining && sn < remaining) {
        sh_prefix = (prefix << 8) | (unsigned)tid;
        sh_rem = remaining - sn;
      }
    }
    __syncthreads();
    prefix = sh_prefix; remaining = sh_rem;
    __syncthreads();
  }
  unsigned T = prefix;

  int cntA = 0, cntT = 0;
#pragma unroll
  for (int e = 0; e < CH2; e++) {
    cntA += (keys[e] > T);
    cntT += (keys[e] == T);
  }
  int totA, totT;
  int offA = scan_excl_1024(cntA, lds, &totA);
  int offT = scan_excl_1024(cntT, lds, &totT);
  int* out = nsel + (size_t)b * cKN;
  int oa = offA, ot = offT;
  for (int e = 0; e < CH2; e++) {
    unsigned key = keys[e];
    if (key > T) { out[oa++] = base + e; }
    else if (key == T) { if (ot < remaining) out[totA + ot] = base + e; ot++; }
  }
}

// ---------------- fused loss GEMM + last-block finalize ----------------
__global__ __launch_bounds__(256) void k_loss(const __hip_bfloat16* G, const __hip_bfloat16* cf,
                                              const int* nsel, int* scal, float2* ELp, float* out) {
  __shared__ float sE[4][64];
  __shared__ float sL[4][64];
  __shared__ int sIsLast;
  __shared__ float sred[4];
  int b = blockIdx.z, chunk = blockIdx.y;
  int P_valid = scal[b * 16 + 1];
  int KEEP = scal[b * 16 + 3];
  int wave = threadIdx.x >> 6, lane = threadIdx.x & 63;
  int lr = lane & 15, quad = lane >> 4;
  int rowbase = blockIdx.x * 64;
  const __bf16* Gb  = (const __bf16*)G  + (size_t)b * cP * cC;
  const __bf16* cfb = (const __bf16*)cf + (size_t)b * cKC * cC;
  const int* nselb = nsel + (size_t)b * cKN;

  if (P_valid >= 2) {
    bf16x8 afr[4][2];
#pragma unroll
    for (int rt = 0; rt < 4; rt++) {
      const __bf16* src = Gb + (size_t)(rowbase + rt * 16 + lr) * cC + quad * 8;
      afr[rt][0] = *(const bf16x8*)src;
      afr[rt][1] = *(const bf16x8*)(src + 32);
    }
    float eacc[4][4] = {};
    float lacc[4][4] = {};
    int ct0 = chunk * cTPC;
    for (int ct = ct0 + wave; ct < ct0 + cTPC; ct += 4) {
      int tb = ct * 16;
      bool is_pos = tb < cP;
      int vlimit = is_pos ? P_valid : (cP + KEEP);
      if (tb >= vlimit) continue;                       // wave-uniform skip
      bool all_valid = (tb + 16) <= vlimit;
      bool has_diag = is_pos && (tb >= rowbase) && (tb < rowbase + 64);
      const __bf16* bsrc;
      if (is_pos) {
        bsrc = Gb + (size_t)(tb + lr) * cC + quad * 8;
      } else {
        int k = tb - cP + lr;
        int kk = min(k, KEEP - 1);
        int idx = nselb[kk];
        bsrc = cfb + (size_t)idx * cC + quad * 8;
      }
      bf16x8 b0 = *(const bf16x8*)bsrc;
      bf16x8 b1 = *(const bf16x8*)(bsrc + 32);
      f32x4 acc[4];
#pragma unroll
      for (int rt = 0; rt < 4; rt++) {
        f32x4 a = {0, 0, 0, 0};
        a = mfma16(afr[rt][0], b0, a);
        a = mfma16(afr[rt][1], b1, a);
        acc[rt] = a;
      }
      if (all_valid && !has_diag) {
        if (is_pos) {
#pragma unroll
          for (int rt = 0; rt < 4; rt++)
#pragma unroll
            for (int r = 0; r < 4; r++) {
              float logit = acc[rt][r] * cTEMP_INV;
              eacc[rt][r] += __expf(logit);
              lacc[rt][r] += logit;
            }
        } else {
#pragma unroll
          for (int rt = 0; rt < 4; rt++)
#pragma unroll
            for (int r = 0; r < 4; r++)
              eacc[rt][r] += __expf(acc[rt][r] * cTEMP_INV);
        }
      } else {
        bool colv = (tb + lr) < vlimit;
#pragma unroll
        for (int rt = 0; rt < 4; rt++) {
          int rb = rowbase + rt * 16 + quad * 4;
#pragma unroll
          for (int r = 0; r < 4; r++) {
            float logit = acc[rt][r] * cTEMP_INV;
            bool use = colv && !(has_diag && (tb + lr) == (rb + r));
            float e = __expf(logit);
            eacc[rt][r] += use ? e : 0.0f;
            if (is_pos) lacc[rt][r] += use ? logit : 0.0f;
          }
        }
      }
    }
#pragma unroll
    for (int rt = 0; rt < 4; rt++) {
#pragma unroll
      for (int r = 0; r < 4; r++) {
        float e = eacc[rt][r], l = lacc[rt][r];
#pragma unroll
        for (int d = 1; d < 16; d <<= 1) {
          e += __shfl_xor(e, d);
          l += __shfl_xor(l, d);
        }
        if (lr == 0) {
          sE[wave][rt * 16 + quad * 4 + r] = e;
          sL[wave][rt * 16 + quad * 4 + r] = l;
        }
      }
    }
    __syncthreads();
    if (threadIdx.x < 64) {
      int row = rowbase + threadIdx.x;
      float E = sE[0][threadIdx.x] + sE[1][threadIdx.x] + sE[2][threadIdx.x] + sE[3][threadIdx.x];
      float L = sL[0][threadIdx.x] + sL[1][threadIdx.x] + sL[2][threadIdx.x] + sL[3][threadIdx.x];
      ELp[((size_t)chunk * cB + b) * cP + row] = make_float2(E, L);
    }
  }

  // ---- last-block finalize (fence + device-scope counter) ----
  __threadfence();
  if (threadIdx.x == 0) sIsLast = (atomicAdd(&scal[15], 1) == cLOSS_BLOCKS - 1) ? 1 : 0;
  __syncthreads();
  if (!sIsLast) return;
  __threadfence();

  float tot = 0.f;
  int cnt = 0;
  for (int bb = 0; bb < cB; bb++) {
    int Pv = scal[bb * 16 + 1];
    if (Pv < 2) continue;
    float inv = 1.0f / (float)(Pv - 1);
    float s = 0.f;
    for (int row = threadIdx.x; row < cP; row += 256) {
      if (row < Pv) {
        float E = 0.f, L = 0.f;
#pragma unroll
        for (int ch = 0; ch < cNCH; ch++) {
          float2 el = ELp[((size_t)ch * cB + bb) * cP + row];
          E += el.x; L += el.y;
        }
        s += logf(E) - L * inv;
      }
    }
#pragma unroll
    for (int d = 1; d < 64; d <<= 1) s += __shfl_xor(s, d);
    __syncthreads();
    if ((threadIdx.x & 63) == 0) sred[threadIdx.x >> 6] = s;
    __syncthreads();
    if (threadIdx.x == 0) {
      tot += (sred[0] + sred[1] + sred[2] + sred[3]) / (float)Pv;
      cnt++;
    }
  }
  if (threadIdx.x == 0) out[0] = tot / (float)(cnt > 0 ? cnt : 1);
}

extern "C" void kernel_launch(void* const* d_in, const int* in_sizes, int n_in,
                              void* d_out, int out_size, void* d_ws, size_t ws_size,
                              hipStream_t stream) {
  const float* feat = (const float*)d_in[0];
  const int* labels = (const int*)d_in[1];
  char* ws = (char*)d_ws;
  unsigned char* fg  = (unsigned char*)(ws + off_fg);
  unsigned char* tmp = (unsigned char*)(ws + off_tmp);
  unsigned char* rim = (unsigned char*)(ws + off_rim);
  int* pidx = (int*)(ws + off_pidx);
  int* cidx = (int*)(ws + off_cidx);
  int* scal = (int*)(ws + off_scal);
  float2* ELp = (float2*)(ws + off_EL);
  float* msim = (float*)(ws + off_msim);
  int* nsel = (int*)(ws + off_nsel);
  __hip_bfloat16* G  = (__hip_bfloat16*)(ws + off_G);
  __hip_bfloat16* cf = (__hip_bfloat16*)(ws + off_cf);
  int* blkcnt = (int*)(ws + off_bcnt);
  int2* blkoff = (int2*)(ws + off_boff);
  float* out = (float*)d_out;

  k_fg_hdil<<<cB * cHW / 8 / 256, 256, 0, stream>>>(labels, fg, tmp);
  k_vdil_count<<<dim3(cNB, cB), 256, 0, stream>>>(tmp, fg, rim, blkcnt);
  k_offsets<<<cB, 128, 0, stream>>>(blkcnt, blkoff, scal);
  k_scatter<<<dim3(cNB, cB), 256, 0, stream>>>(fg, rim, blkoff, scal, pidx, cidx);
  k_gather_norm<<<dim3(cP / 256 + cKC / 256, cB), 256, 0, stream>>>(feat, pidx, cidx, G, cf);
  k_mine<<<dim3(cKC / cMCB, 2, cB), 256, 0, stream>>>(G, cf, scal, msim);
  k_selneg<<<cB, 1024, 0, stream>>>(msim, nsel, scal);
  k_loss<<<dim3(cP / 64, cNCH, cB), 256, 0, stream>>>(G, cf, nsel, scal, ELp, out);
}

// Round 7
// 406.344 us; speedup vs baseline: 1.0792x; 1.0792x over previous
//
#include <hip/hip_runtime.h>
#include <hip/hip_bf16.h>

#define DEVI __device__ __forceinline__

static constexpr int cB = 4, cC = 64, cH = 384, cW = 384;
static constexpr int cHW = cH * cW;           // 147456
static constexpr int cP  = 2048;              // MAX_POS
static constexpr int cKC = 20480;             // candidate pool
static constexpr int cKN = 10240;             // max negatives
static constexpr int cNT = cP + cKN;          // 12288 rows of G = [pf; nf]
static constexpr float cTEMP_INV = 10.0f;     // 1/TEMP
static constexpr int cMR = 8;                 // rows per mask/scatter block
static constexpr int cNB = cH / cMR;          // 48 blocks per image
static constexpr int cCHUNK = cMR * cW;       // 3072 px per block
static constexpr int cNCH = 8;                // column chunks for k_loss
static constexpr int cTPC = (cNT / 16) / cNCH; // 96 col tiles per chunk
static constexpr int cMTW = 5;                // col tiles per wave in k_mine
static constexpr int cMCB = 320;              // cols per block in k_mine
static constexpr int cLOSS_BLOCKS = (cP / 64) * cNCH * cB;  // 1024

using f32x4  = __attribute__((ext_vector_type(4))) float;
using bf16x8 = __attribute__((ext_vector_type(8))) __bf16;

// ---- workspace layout (bytes) ----
static constexpr size_t off_fg   = 0;
static constexpr size_t off_rim  = off_fg   + (size_t)cB * cHW;
static constexpr size_t off_pidx = off_rim  + (size_t)cB * cHW;
static constexpr size_t off_cidx = off_pidx + (size_t)cB * cP * 4;
static constexpr size_t off_scal = off_cidx + (size_t)cB * cKC * 4;
static constexpr size_t off_EL   = off_scal + 256;
static constexpr size_t off_msim = off_EL   + (size_t)cNCH * cB * cP * 8;
static constexpr size_t off_nsel = off_msim + (size_t)cB * 2 * cKC * 4;
static constexpr size_t off_G    = off_nsel + (size_t)cB * cKN * 4;
static constexpr size_t off_cf   = off_G    + (size_t)cB * cNT * cC * 2;
static constexpr size_t off_bcnt = off_cf   + (size_t)cB * cKC * cC * 2;
// total ≈ 19 MB

DEVI f32x4 mfma16(bf16x8 a, bf16x8 b, f32x4 c) {
  return __builtin_amdgcn_mfma_f32_16x16x32_bf16(a, b, c, 0, 0, 0);
}

// ---------------- fused mask pipeline: fg, 11x11 dilation, rim, per-block counts ----------------
// one block per 8 image rows; 18-row fg/hdil halo recomputed in LDS
__global__ __launch_bounds__(384) void k_mask(const int* labels, unsigned char* fg,
                                              unsigned char* rim, int* blkcnt) {
  __shared__ unsigned char sdil[18 * cW];   // hdil for rows r0-5 .. r0+12
  __shared__ unsigned char sfg[cMR * cW];
  __shared__ int red[384];
  int b = blockIdx.y, blk = blockIdx.x, tid = threadIdx.x;
  int r0 = blk * cMR;
  const int* lab = labels + (size_t)b * cHW;
  // context phase: 18 rows x 48 chunks of 8 px
  for (int ci = tid; ci < 18 * 48; ci += 384) {
    int cr = ci / 48, cx = (ci % 48) * 8;
    int gy = r0 - 5 + cr;
    unsigned m = 0;
    if (gy >= 0 && gy < cH) {
      const int* lrow = lab + gy * cW;
#pragma unroll
      for (int j = 0; j < 18; j++) {
        int x = cx - 5 + j;
        int v = (x >= 0 && x < cW) ? (lrow[x] > 0) : 0;
        m |= (unsigned)v << j;
      }
    }
    unsigned long long dil8 = 0, fg8 = 0;
#pragma unroll
    for (int e = 0; e < 8; e++) {
      dil8 |= (unsigned long long)(((m >> e) & 0x7FFu) ? 1u : 0u) << (8 * e);
      fg8  |= (unsigned long long)((m >> (e + 5)) & 1u) << (8 * e);
    }
    *(unsigned long long*)&sdil[cr * cW + cx] = dil8;
    if (cr >= 5 && cr < 13) *(unsigned long long*)&sfg[(cr - 5) * cW + cx] = fg8;
  }
  __syncthreads();
  // own phase: 8 rows x 48 chunks = 384 chunks, one per thread
  int cr = tid / 48, cx = (tid % 48) * 8;
  unsigned long long fv = *(unsigned long long*)&sfg[cr * cW + cx];
  unsigned long long dv = 0;
#pragma unroll
  for (int dy = 0; dy < 11; dy++)
    dv |= *(unsigned long long*)&sdil[(cr + dy) * cW + cx];
  unsigned long long pk = dv & (fv ^ 0x0101010101010101ULL);
  size_t gbase = (size_t)b * cHW + (size_t)(r0 + cr) * cW + cx;
  *(unsigned long long*)(fg + gbase)  = fv;
  *(unsigned long long*)(rim + gbase) = pk;
  int cfg  = __popcll(fv & 0x0101010101010101ULL);
  int crim = __popcll(pk & 0x0101010101010101ULL);
  red[tid] = cfg | (crim << 16);
  __syncthreads();
  if (tid < 128) red[tid] += red[tid + 128] + red[tid + 256];
  __syncthreads();
  for (int s = 64; s > 0; s >>= 1) {
    if (tid < s) red[tid] += red[tid + s];
    __syncthreads();
  }
  if (tid == 0) blkcnt[b * cNB + blk] = red[0];
}

__device__ int scan_excl_384(int v, int* lds) {
  int tid = threadIdx.x;
  lds[tid] = v;
  __syncthreads();
  for (int d = 1; d < 384; d <<= 1) {
    int t = (tid >= d) ? lds[tid - d] : 0;
    __syncthreads();
    lds[tid] += t;
    __syncthreads();
  }
  int e = lds[tid] - v;
  __syncthreads();
  return e;
}

// raster-order scatter (self-computed offsets): fg->pidx (fill !fg), rim->cidx (fill !rim)
__global__ __launch_bounds__(384) void k_scatter(const unsigned char* fg, const unsigned char* rim,
                                                 const int* blkcnt, int* scal,
                                                 int* pidx, int* cidx) {
  __shared__ int scnt[cNB];
  __shared__ int lds[384];
  int b = blockIdx.y, blk = blockIdx.x, tid = threadIdx.x;
  if (tid < cNB) scnt[tid] = blkcnt[b * cNB + tid];
  __syncthreads();
  int offx = 0, offy = 0, nfg = 0, nrim = 0;
  for (int j = 0; j < cNB; j++) {
    int v = scnt[j];
    int f = v & 0xffff, r = v >> 16;
    if (j < blk) { offx += f; offy += r; }
    nfg += f; nrim += r;
  }
  if (blk == 0 && tid == 0) {
    scal[b * 16 + 0] = nfg;
    scal[b * 16 + 1] = min(nfg, cP);    // P_valid
    scal[b * 16 + 2] = min(nrim, cKC);  // C_valid
    scal[b * 16 + 4] = nrim;
    if (b == 0) scal[15] = 0;           // completion counter for k_loss
  }
  bool needf = (offx < cP)  || (nfg  < cP);
  bool needr = (offy < cKC) || (nrim < cKC);
  if (!needf && !needr) return;
  int base = blk * cCHUNK + tid * 8;
  const unsigned char* fgb  = fg  + (size_t)b * cHW;
  const unsigned char* rimb = rim + (size_t)b * cHW;
  unsigned long long fv = *(const unsigned long long*)(fgb + base);
  unsigned long long rv = *(const unsigned long long*)(rimb + base);
  int cfg  = __popcll(fv & 0x0101010101010101ULL);
  int crim = __popcll(rv & 0x0101010101010101ULL);
  int ex = scan_excl_384(cfg | (crim << 16), lds);
  int of  = offx + (ex & 0xffff);
  int orr = offy + (ex >> 16);
  int* pout = pidx + (size_t)b * cP;
  int* cout = cidx + (size_t)b * cKC;
#pragma unroll
  for (int e = 0; e < 8; e++) {
    int p = base + e;
    int f = (int)((fv >> (8 * e)) & 1);
    int r = (int)((rv >> (8 * e)) & 1);
    if (f) { if (of < cP) pout[of] = p; of++; }
    else if (nfg < cP) { int o = nfg + (p - of); if (o < cP) pout[o] = p; }
    if (r) { if (orr < cKC) cout[orr] = p; orr++; }
    else if (nrim < cKC) { int o = nrim + (p - orr); if (o < cKC) cout[o] = p; }
  }
}

// ---------------- gather + L2-normalize -> bf16 rows (both pools, one launch) ----------------
__global__ __launch_bounds__(256) void k_gather_norm(const float* feat, const int* pidx, const int* cidx,
                                                     __hip_bfloat16* G, __hip_bfloat16* cf) {
  int b = blockIdx.y;
  int bx = blockIdx.x;
  int p;
  __hip_bfloat16* out;
  if (bx < cP / 256) {
    int i = bx * 256 + threadIdx.x;
    p = pidx[(size_t)b * cP + i];
    out = G + (size_t)b * cNT * cC + (size_t)i * cC;
  } else {
    int i = (bx - cP / 256) * 256 + threadIdx.x;
    p = cidx[(size_t)b * cKC + i];
    out = cf + (size_t)b * cKC * cC + (size_t)i * cC;
  }
  const float* fb = feat + (size_t)b * cC * cHW + p;
  float v[cC];
  float ss = 0.f;
#pragma unroll
  for (int c = 0; c < cC; c++) { float t = fb[(size_t)c * cHW]; v[c] = t; ss += t * t; }
  float sc = 1.0f / fmaxf(sqrtf(ss), 1e-8f);
#pragma unroll
  for (int c = 0; c < cC; c++) out[c] = __float2bfloat16(v[c] * sc);
}

// ---------------- hard-negative mining: column max of pf @ cf^T ----------------
// 80 cols/wave, 320/block; A chunk LDS-staged in two 64KB halves (XOR-swizzled)
__global__ __launch_bounds__(256) void k_mine(const __hip_bfloat16* G, const __hip_bfloat16* cf,
                                              const int* scal, float* msim) {
  __shared__ int4 smem[4096];           // 64 KB: 512 rows x 8 x 16B, swizzled
  int b = blockIdx.z, rc = blockIdx.y;
  int P_valid = scal[b * 16 + 1];
  int wave = threadIdx.x >> 6, lane = threadIdx.x & 63;
  int lr = lane & 15, quad = lane >> 4;
  int colbase = blockIdx.x * cMCB + wave * (cMTW * 16);
  float* msout = msim + ((size_t)b * 2 + rc) * cKC;
  int chunk_lo = rc * 1024;
  if (chunk_lo >= P_valid) {
    if (quad == 0) {
#pragma unroll
      for (int tt = 0; tt < cMTW; tt++) msout[colbase + tt * 16 + lr] = -INFINITY;
    }
    return;
  }
  const int4* pf4 = (const int4*)((const __bf16*)(G + (size_t)b * cNT * cC)) + (size_t)chunk_lo * 8;
  const __bf16* cfb = (const __bf16*)(cf + (size_t)b * cKC * cC);

  bf16x8 bfr[cMTW][2];
#pragma unroll
  for (int tt = 0; tt < cMTW; tt++) {
    const __bf16* src = cfb + (size_t)(colbase + tt * 16 + lr) * cC + quad * 8;
    bfr[tt][0] = *(const bf16x8*)src;
    bfr[tt][1] = *(const bf16x8*)(src + 32);
  }
  float cmax[cMTW];
#pragma unroll
  for (int tt = 0; tt < cMTW; tt++) cmax[tt] = -INFINITY;

  int swz  = quad ^ (lr & 7);
  int swz2 = (quad + 4) ^ (lr & 7);
  for (int half = 0; half < 2; half++) {
    for (int i = threadIdx.x; i < 4096; i += 256) {
      int r = i >> 3, q = i & 7;
      smem[r * 8 + (q ^ (r & 7))] = pf4[(size_t)(half * 512 + r) * 8 + q];
    }
    __syncthreads();
    int rowg0 = chunk_lo + half * 512;
    bool full = (rowg0 + 512) <= P_valid;
    for (int mtl = 0; mtl < 32; mtl++) {
      int rl = mtl * 16 + lr;
      bf16x8 a0 = *(bf16x8*)&smem[rl * 8 + swz];
      bf16x8 a1 = *(bf16x8*)&smem[rl * 8 + swz2];
      int rb = rowg0 + mtl * 16 + quad * 4;
#pragma unroll
      for (int tt = 0; tt < cMTW; tt++) {
        f32x4 acc = {0, 0, 0, 0};
        acc = mfma16(a0, bfr[tt][0], acc);
        acc = mfma16(a1, bfr[tt][1], acc);
        if (full) {
          cmax[tt] = fmaxf(cmax[tt], fmaxf(fmaxf(acc[0], acc[1]), fmaxf(acc[2], acc[3])));
        } else {
#pragma unroll
          for (int r = 0; r < 4; r++)
            cmax[tt] = fmaxf(cmax[tt], (rb + r) < P_valid ? acc[r] : -INFINITY);
        }
      }
    }
    __syncthreads();
  }
#pragma unroll
  for (int tt = 0; tt < cMTW; tt++) {
    float c = cmax[tt];
    c = fmaxf(c, __shfl_xor(c, 16));
    c = fmaxf(c, __shfl_xor(c, 32));
    if (quad == 0) msout[colbase + tt * 16 + lr] = c;
  }
}

// ---------------- top-KEEP selection (radix threshold; register-resident keys) ----------------
DEVI unsigned f2key(float f) {
  unsigned u = __float_as_uint(f);
  return (u & 0x80000000u) ? ~u : (u | 0x80000000u);
}

__device__ int scan_excl_1024(int v, int* lds, int* total) {
  int tid = threadIdx.x;
  lds[tid] = v;
  __syncthreads();
  for (int d = 1; d < 1024; d <<= 1) {
    int t = (tid >= d) ? lds[tid - d] : 0;
    __syncthreads();
    lds[tid] += t;
    __syncthreads();
  }
  *total = lds[1023];
  int e = lds[tid] - v;
  __syncthreads();
  return e;
}

__global__ __launch_bounds__(1024) void k_selneg(const float* msim, int* nsel, int* scal) {
  __shared__ int hist[256];
  __shared__ int suf[256];
  __shared__ int lds[1024];
  __shared__ unsigned sh_prefix;
  __shared__ int sh_rem;
  int b = blockIdx.x, tid = threadIdx.x;
  const float* ms0 = msim + ((size_t)b * 2 + 0) * cKC;
  const float* ms1 = msim + ((size_t)b * 2 + 1) * cKC;
  int P_valid = scal[b * 16 + 1], C_valid = scal[b * 16 + 2];
  int n_allowed = min(5 * P_valid, cKN);
  int nfin = (P_valid > 0) ? C_valid : 0;
  int KEEP = min(n_allowed, nfin);
  if (tid == 0) scal[b * 16 + 3] = KEEP;
  if (KEEP == 0) return;

  const int CH2 = cKC / 1024;  // 20
  int base = tid * CH2;
  unsigned keys[CH2];
#pragma unroll
  for (int e = 0; e < CH2; e++) {
    int c = base + e;
    keys[e] = (c < C_valid) ? f2key(fmaxf(ms0[c], ms1[c])) : 0u;
  }

  unsigned prefix = 0;
  int remaining = KEEP;
  for (int shift = 24; shift >= 0; shift -= 8) {
    if (tid < 256) hist[tid] = 0;
    __syncthreads();
#pragma unroll
    for (int e = 0; e < CH2; e++) {
      unsigned key = keys[e];
      if (shift == 24 || (key >> (shift + 8)) == prefix)
        atomicAdd(&hist[(key >> shift) & 255], 1);
    }
    __syncthreads();
    if (tid < 256) suf[tid] = hist[tid];
    __syncthreads();
    for (int d = 1; d < 256; d <<= 1) {
      int t = (tid < 256 && tid + d < 256) ? suf[tid + d] : 0;
      __syncthreads();
      if (tid < 256) suf[tid] += t;
      __syncthreads();
    }
    if (tid < 256) {
      int s = suf[tid];
      int sn = (tid < 255) ? suf[tid + 1] : 0;
      if (s >= remaining && sn < remaining) {
        sh_prefix = (prefix << 8) | (unsigned)tid;
        sh_rem = remaining - sn;
      }
    }
    __syncthreads();
    prefix = sh_prefix; remaining = sh_rem;
    __syncthreads();
  }
  unsigned T = prefix;

  int cntA = 0, cntT = 0;
#pragma unroll
  for (int e = 0; e < CH2; e++) {
    cntA += (keys[e] > T);
    cntT += (keys[e] == T);
  }
  int totA, totT;
  int offA = scan_excl_1024(cntA, lds, &totA);
  int offT = scan_excl_1024(cntT, lds, &totT);
  int* out = nsel + (size_t)b * cKN;
  int oa = offA, ot = offT;
  for (int e = 0; e < CH2; e++) {
    unsigned key = keys[e];
    if (key > T) { out[oa++] = base + e; }
    else if (key == T) { if (ot < remaining) out[totA + ot] = base + e; ot++; }
  }
}

// ---------------- gather negatives into G rows [cP, cP+cKN) (zero unused rows) ----------------
__global__ __launch_bounds__(256) void k_gather_neg(const __hip_bfloat16* cf, const int* nsel,
                                                    const int* scal, __hip_bfloat16* G) {
  int b = blockIdx.y;
  int KEEP = scal[b * 16 + 3];
  int t = blockIdx.x * 256 + threadIdx.x;
  int k = t >> 3, part = t & 7;
  if (k >= cKN) return;
  int4 val = {0, 0, 0, 0};
  if (k < KEEP) {
    int src = nsel[(size_t)b * cKN + k];
    val = *(const int4*)((const __bf16*)(cf + (size_t)b * cKC * cC) + (size_t)src * cC + part * 8);
  }
  *(int4*)((__bf16*)(G + (size_t)b * cNT * cC) + (size_t)(cP + k) * cC + part * 8) = val;
}

// ---------------- fused loss GEMM (64 rows/block, per-chunk E/L partials) + last-block finalize ----
__global__ __launch_bounds__(256) void k_loss(const __hip_bfloat16* G, int* scal, float2* ELp, float* out) {
  __shared__ float sE[4][64];
  __shared__ float sL[4][64];
  __shared__ int sIsLast;
  __shared__ float sred[4];
  int b = blockIdx.z, chunk = blockIdx.y;
  int P_valid = scal[b * 16 + 1];
  int KEEP = scal[b * 16 + 3];
  int wave = threadIdx.x >> 6, lane = threadIdx.x & 63;
  int lr = lane & 15, quad = lane >> 4;
  int rowbase = blockIdx.x * 64;
  const __bf16* Gb = (const __bf16*)G + (size_t)b * cNT * cC;

  if (P_valid >= 2) {
    bf16x8 afr[4][2];
#pragma unroll
    for (int rt = 0; rt < 4; rt++) {
      const __bf16* src = Gb + (size_t)(rowbase + rt * 16 + lr) * cC + quad * 8;
      afr[rt][0] = *(const bf16x8*)src;
      afr[rt][1] = *(const bf16x8*)(src + 32);
    }
    float eacc[4][4] = {};
    float lacc[4][4] = {};
    int ct0 = chunk * cTPC;
    for (int ct = ct0 + wave; ct < ct0 + cTPC; ct += 4) {
      int tb = ct * 16;
      bool is_pos = tb < cP;
      int vlimit = is_pos ? P_valid : (cP + KEEP);
      if (tb >= vlimit) continue;                       // wave-uniform skip
      bool all_valid = (tb + 16) <= vlimit;
      bool has_diag = is_pos && (tb >= rowbase) && (tb < rowbase + 64);
      const __bf16* bsrc = Gb + (size_t)(tb + lr) * cC + quad * 8;
      bf16x8 b0 = *(const bf16x8*)bsrc;
      bf16x8 b1 = *(const bf16x8*)(bsrc + 32);
      f32x4 acc[4];
#pragma unroll
      for (int rt = 0; rt < 4; rt++) {
        f32x4 a = {0, 0, 0, 0};
        a = mfma16(afr[rt][0], b0, a);
        a = mfma16(afr[rt][1], b1, a);
        acc[rt] = a;
      }
      if (all_valid && !has_diag) {
        if (is_pos) {
#pragma unroll
          for (int rt = 0; rt < 4; rt++)
#pragma unroll
            for (int r = 0; r < 4; r++) {
              float logit = acc[rt][r] * cTEMP_INV;
              eacc[rt][r] += __expf(logit);
              lacc[rt][r] += logit;
            }
        } else {
#pragma unroll
          for (int rt = 0; rt < 4; rt++)
#pragma unroll
            for (int r = 0; r < 4; r++)
              eacc[rt][r] += __expf(acc[rt][r] * cTEMP_INV);
        }
      } else {
        bool colv = (tb + lr) < vlimit;
#pragma unroll
        for (int rt = 0; rt < 4; rt++) {
          int rb = rowbase + rt * 16 + quad * 4;
#pragma unroll
          for (int r = 0; r < 4; r++) {
            float logit = acc[rt][r] * cTEMP_INV;
            bool use = colv && !(has_diag && (tb + lr) == (rb + r));
            float e = __expf(logit);
            eacc[rt][r] += use ? e : 0.0f;
            if (is_pos) lacc[rt][r] += use ? logit : 0.0f;
          }
        }
      }
    }
#pragma unroll
    for (int rt = 0; rt < 4; rt++) {
#pragma unroll
      for (int r = 0; r < 4; r++) {
        float e = eacc[rt][r], l = lacc[rt][r];
#pragma unroll
        for (int d = 1; d < 16; d <<= 1) {
          e += __shfl_xor(e, d);
          l += __shfl_xor(l, d);
        }
        if (lr == 0) {
          sE[wave][rt * 16 + quad * 4 + r] = e;
          sL[wave][rt * 16 + quad * 4 + r] = l;
        }
      }
    }
    __syncthreads();
    if (threadIdx.x < 64) {
      int row = rowbase + threadIdx.x;
      float E = sE[0][threadIdx.x] + sE[1][threadIdx.x] + sE[2][threadIdx.x] + sE[3][threadIdx.x];
      float L = sL[0][threadIdx.x] + sL[1][threadIdx.x] + sL[2][threadIdx.x] + sL[3][threadIdx.x];
      ELp[((size_t)chunk * cB + b) * cP + row] = make_float2(E, L);
    }
  }

  // ---- last-block finalize (fence + device-scope counter) ----
  __threadfence();
  if (threadIdx.x == 0) sIsLast = (atomicAdd(&scal[15], 1) == cLOSS_BLOCKS - 1) ? 1 : 0;
  __syncthreads();
  if (!sIsLast) return;
  __threadfence();

  float tot = 0.f;
  int cnt = 0;
  for (int bb = 0; bb < cB; bb++) {
    int Pv = scal[bb * 16 + 1];
    if (Pv < 2) continue;
    float inv = 1.0f / (float)(Pv - 1);
    float s = 0.f;
    for (int row = threadIdx.x; row < cP; row += 256) {
      if (row < Pv) {
        float E = 0.f, L = 0.f;
#pragma unroll
        for (int ch = 0; ch < cNCH; ch++) {
          float2 el = ELp[((size_t)ch * cB + bb) * cP + row];
          E += el.x; L += el.y;
        }
        s += logf(E) - L * inv;
      }
    }
#pragma unroll
    for (int d = 1; d < 64; d <<= 1) s += __shfl_xor(s, d);
    __syncthreads();
    if ((threadIdx.x & 63) == 0) sred[threadIdx.x >> 6] = s;
    __syncthreads();
    if (threadIdx.x == 0) {
      tot += (sred[0] + sred[1] + sred[2] + sred[3]) / (float)Pv;
      cnt++;
    }
  }
  if (threadIdx.x == 0) out[0] = tot / (float)(cnt > 0 ? cnt : 1);
}

extern "C" void kernel_launch(void* const* d_in, const int* in_sizes, int n_in,
                              void* d_out, int out_size, void* d_ws, size_t ws_size,
                              hipStream_t stream) {
  const float* feat = (const float*)d_in[0];
  const int* labels = (const int*)d_in[1];
  char* ws = (char*)d_ws;
  unsigned char* fg  = (unsigned char*)(ws + off_fg);
  unsigned char* rim = (unsigned char*)(ws + off_rim);
  int* pidx = (int*)(ws + off_pidx);
  int* cidx = (int*)(ws + off_cidx);
  int* scal = (int*)(ws + off_scal);
  float2* ELp = (float2*)(ws + off_EL);
  float* msim = (float*)(ws + off_msim);
  int* nsel = (int*)(ws + off_nsel);
  __hip_bfloat16* G  = (__hip_bfloat16*)(ws + off_G);
  __hip_bfloat16* cf = (__hip_bfloat16*)(ws + off_cf);
  int* blkcnt = (int*)(ws + off_bcnt);
  float* out = (float*)d_out;

  k_mask<<<dim3(cNB, cB), 384, 0, stream>>>(labels, fg, rim, blkcnt);
  k_scatter<<<dim3(cNB, cB), 384, 0, stream>>>(fg, rim, blkcnt, scal, pidx, cidx);
  k_gather_norm<<<dim3(cP / 256 + cKC / 256, cB), 256, 0, stream>>>(feat, pidx, cidx, G, cf);
  k_mine<<<dim3(cKC / cMCB, 2, cB), 256, 0, stream>>>(G, cf, scal, msim);
  k_selneg<<<cB, 1024, 0, stream>>>(msim, nsel, scal);
  k_gather_neg<<<dim3(cKN * 8 / 256, cB), 256, 0, stream>>>(cf, nsel, scal, G);
  k_loss<<<dim3(cP / 64, cNCH, cB), 256, 0, stream>>>(G, scal, ELp, out);
}

// Round 8
// 348.543 us; speedup vs baseline: 1.2582x; 1.1658x over previous
//
#include <hip/hip_runtime.h>
#include <hip/hip_bf16.h>

#define DEVI __device__ __forceinline__

static constexpr int cB = 4, cC = 64, cH = 384, cW = 384;
static constexpr int cHW = cH * cW;           // 147456
static constexpr int cP  = 2048;              // MAX_POS
static constexpr int cKC = 20480;             // candidate pool
static constexpr int cKN = 10240;             // max negatives
static constexpr int cNT = cP + cKN;          // 12288 rows of G = [pf; nf]
static constexpr float cTEMP_INV = 10.0f;     // 1/TEMP
static constexpr int cMR = 8;                 // rows per mask/scatter block
static constexpr int cNB = cH / cMR;          // 48 blocks per image
static constexpr int cCHUNK = cMR * cW;       // 3072 px per block
static constexpr int cNCH = 8;                // column chunks for k_loss
static constexpr int cTPC = (cNT / 16) / cNCH; // 96 col tiles per chunk
static constexpr int cMTW = 5;                // col tiles per wave in k_mine
static constexpr int cMCB = 320;              // cols per block in k_mine

using f32x4  = __attribute__((ext_vector_type(4))) float;
using bf16x8 = __attribute__((ext_vector_type(8))) __bf16;

// ---- workspace layout (bytes) ----
static constexpr size_t off_fg   = 0;
static constexpr size_t off_rim  = off_fg   + (size_t)cB * cHW;
static constexpr size_t off_pidx = off_rim  + (size_t)cB * cHW;
static constexpr size_t off_cidx = off_pidx + (size_t)cB * cP * 4;
static constexpr size_t off_scal = off_cidx + (size_t)cB * cKC * 4;
static constexpr size_t off_EL   = off_scal + 256;
static constexpr size_t off_msim = off_EL   + (size_t)cNCH * cB * cP * 8;
static constexpr size_t off_nsel = off_msim + (size_t)cB * 2 * cKC * 4;
static constexpr size_t off_G    = off_nsel + (size_t)cB * cKN * 4;
static constexpr size_t off_cf   = off_G    + (size_t)cB * cNT * cC * 2;
static constexpr size_t off_bcnt = off_cf   + (size_t)cB * cKC * cC * 2;
// total ≈ 19 MB

DEVI f32x4 mfma16(bf16x8 a, bf16x8 b, f32x4 c) {
  return __builtin_amdgcn_mfma_f32_16x16x32_bf16(a, b, c, 0, 0, 0);
}

// ---------------- fused mask pipeline: fg, 11x11 dilation, rim, per-block counts ----------------
__global__ __launch_bounds__(384) void k_mask(const int* labels, unsigned char* fg,
                                              unsigned char* rim, int* blkcnt) {
  __shared__ unsigned char sdil[18 * cW];   // hdil for rows r0-5 .. r0+12
  __shared__ unsigned char sfg[cMR * cW];
  __shared__ int red[384];
  int b = blockIdx.y, blk = blockIdx.x, tid = threadIdx.x;
  int r0 = blk * cMR;
  const int* lab = labels + (size_t)b * cHW;
  for (int ci = tid; ci < 18 * 48; ci += 384) {
    int cr = ci / 48, cx = (ci % 48) * 8;
    int gy = r0 - 5 + cr;
    unsigned m = 0;
    if (gy >= 0 && gy < cH) {
      const int* lrow = lab + gy * cW;
#pragma unroll
      for (int j = 0; j < 18; j++) {
        int x = cx - 5 + j;
        int v = (x >= 0 && x < cW) ? (lrow[x] > 0) : 0;
        m |= (unsigned)v << j;
      }
    }
    unsigned long long dil8 = 0, fg8 = 0;
#pragma unroll
    for (int e = 0; e < 8; e++) {
      dil8 |= (unsigned long long)(((m >> e) & 0x7FFu) ? 1u : 0u) << (8 * e);
      fg8  |= (unsigned long long)((m >> (e + 5)) & 1u) << (8 * e);
    }
    *(unsigned long long*)&sdil[cr * cW + cx] = dil8;
    if (cr >= 5 && cr < 13) *(unsigned long long*)&sfg[(cr - 5) * cW + cx] = fg8;
  }
  __syncthreads();
  int cr = tid / 48, cx = (tid % 48) * 8;
  unsigned long long fv = *(unsigned long long*)&sfg[cr * cW + cx];
  unsigned long long dv = 0;
#pragma unroll
  for (int dy = 0; dy < 11; dy++)
    dv |= *(unsigned long long*)&sdil[(cr + dy) * cW + cx];
  unsigned long long pk = dv & (fv ^ 0x0101010101010101ULL);
  size_t gbase = (size_t)b * cHW + (size_t)(r0 + cr) * cW + cx;
  *(unsigned long long*)(fg + gbase)  = fv;
  *(unsigned long long*)(rim + gbase) = pk;
  int cfg  = __popcll(fv & 0x0101010101010101ULL);
  int crim = __popcll(pk & 0x0101010101010101ULL);
  red[tid] = cfg | (crim << 16);
  __syncthreads();
  if (tid < 128) red[tid] += red[tid + 128] + red[tid + 256];
  __syncthreads();
  for (int s = 64; s > 0; s >>= 1) {
    if (tid < s) red[tid] += red[tid + s];
    __syncthreads();
  }
  if (tid == 0) blkcnt[b * cNB + blk] = red[0];
}

__device__ int scan_excl_384(int v, int* lds) {
  int tid = threadIdx.x;
  lds[tid] = v;
  __syncthreads();
  for (int d = 1; d < 384; d <<= 1) {
    int t = (tid >= d) ? lds[tid - d] : 0;
    __syncthreads();
    lds[tid] += t;
    __syncthreads();
  }
  int e = lds[tid] - v;
  __syncthreads();
  return e;
}

// raster-order scatter (self-computed offsets): fg->pidx (fill !fg), rim->cidx (fill !rim)
__global__ __launch_bounds__(384) void k_scatter(const unsigned char* fg, const unsigned char* rim,
                                                 const int* blkcnt, int* scal,
                                                 int* pidx, int* cidx) {
  __shared__ int scnt[cNB];
  __shared__ int lds[384];
  int b = blockIdx.y, blk = blockIdx.x, tid = threadIdx.x;
  if (tid < cNB) scnt[tid] = blkcnt[b * cNB + tid];
  __syncthreads();
  int offx = 0, offy = 0, nfg = 0, nrim = 0;
  for (int j = 0; j < cNB; j++) {
    int v = scnt[j];
    int f = v & 0xffff, r = v >> 16;
    if (j < blk) { offx += f; offy += r; }
    nfg += f; nrim += r;
  }
  if (blk == 0 && tid == 0) {
    scal[b * 16 + 0] = nfg;
    scal[b * 16 + 1] = min(nfg, cP);    // P_valid
    scal[b * 16 + 2] = min(nrim, cKC);  // C_valid
    scal[b * 16 + 4] = nrim;
  }
  bool needf = (offx < cP)  || (nfg  < cP);
  bool needr = (offy < cKC) || (nrim < cKC);
  if (!needf && !needr) return;
  int base = blk * cCHUNK + tid * 8;
  const unsigned char* fgb  = fg  + (size_t)b * cHW;
  const unsigned char* rimb = rim + (size_t)b * cHW;
  unsigned long long fv = *(const unsigned long long*)(fgb + base);
  unsigned long long rv = *(const unsigned long long*)(rimb + base);
  int cfg  = __popcll(fv & 0x0101010101010101ULL);
  int crim = __popcll(rv & 0x0101010101010101ULL);
  int ex = scan_excl_384(cfg | (crim << 16), lds);
  int of  = offx + (ex & 0xffff);
  int orr = offy + (ex >> 16);
  int* pout = pidx + (size_t)b * cP;
  int* cout = cidx + (size_t)b * cKC;
#pragma unroll
  for (int e = 0; e < 8; e++) {
    int p = base + e;
    int f = (int)((fv >> (8 * e)) & 1);
    int r = (int)((rv >> (8 * e)) & 1);
    if (f) { if (of < cP) pout[of] = p; of++; }
    else if (nfg < cP) { int o = nfg + (p - of); if (o < cP) pout[o] = p; }
    if (r) { if (orr < cKC) cout[orr] = p; orr++; }
    else if (nrim < cKC) { int o = nrim + (p - orr); if (o < cKC) cout[o] = p; }
  }
}

// ---------------- gather + L2-normalize -> bf16 rows (both pools, one launch) ----------------
__global__ __launch_bounds__(256) void k_gather_norm(const float* feat, const int* pidx, const int* cidx,
                                                     __hip_bfloat16* G, __hip_bfloat16* cf) {
  int b = blockIdx.y;
  int bx = blockIdx.x;
  int p;
  __hip_bfloat16* out;
  if (bx < cP / 256) {
    int i = bx * 256 + threadIdx.x;
    p = pidx[(size_t)b * cP + i];
    out = G + (size_t)b * cNT * cC + (size_t)i * cC;
  } else {
    int i = (bx - cP / 256) * 256 + threadIdx.x;
    p = cidx[(size_t)b * cKC + i];
    out = cf + (size_t)b * cKC * cC + (size_t)i * cC;
  }
  const float* fb = feat + (size_t)b * cC * cHW + p;
  float v[cC];
  float ss = 0.f;
#pragma unroll
  for (int c = 0; c < cC; c++) { float t = fb[(size_t)c * cHW]; v[c] = t; ss += t * t; }
  float sc = 1.0f / fmaxf(sqrtf(ss), 1e-8f);
#pragma unroll
  for (int c = 0; c < cC; c++) out[c] = __float2bfloat16(v[c] * sc);
}

// ---------------- hard-negative mining: column max of pf @ cf^T ----------------
__global__ __launch_bounds__(256) void k_mine(const __hip_bfloat16* G, const __hip_bfloat16* cf,
                                              const int* scal, float* msim) {
  __shared__ int4 smem[4096];           // 64 KB: 512 rows x 8 x 16B, swizzled
  int b = blockIdx.z, rc = blockIdx.y;
  int P_valid = scal[b * 16 + 1];
  int wave = threadIdx.x >> 6, lane = threadIdx.x & 63;
  int lr = lane & 15, quad = lane >> 4;
  int colbase = blockIdx.x * cMCB + wave * (cMTW * 16);
  float* msout = msim + ((size_t)b * 2 + rc) * cKC;
  int chunk_lo = rc * 1024;
  if (chunk_lo >= P_valid) {
    if (quad == 0) {
#pragma unroll
      for (int tt = 0; tt < cMTW; tt++) msout[colbase + tt * 16 + lr] = -INFINITY;
    }
    return;
  }
  const int4* pf4 = (const int4*)((const __bf16*)(G + (size_t)b * cNT * cC)) + (size_t)chunk_lo * 8;
  const __bf16* cfb = (const __bf16*)(cf + (size_t)b * cKC * cC);

  bf16x8 bfr[cMTW][2];
#pragma unroll
  for (int tt = 0; tt < cMTW; tt++) {
    const __bf16* src = cfb + (size_t)(colbase + tt * 16 + lr) * cC + quad * 8;
    bfr[tt][0] = *(const bf16x8*)src;
    bfr[tt][1] = *(const bf16x8*)(src + 32);
  }
  float cmax[cMTW];
#pragma unroll
  for (int tt = 0; tt < cMTW; tt++) cmax[tt] = -INFINITY;

  int swz  = quad ^ (lr & 7);
  int swz2 = (quad + 4) ^ (lr & 7);
  for (int half = 0; half < 2; half++) {
    for (int i = threadIdx.x; i < 4096; i += 256) {
      int r = i >> 3, q = i & 7;
      smem[r * 8 + (q ^ (r & 7))] = pf4[(size_t)(half * 512 + r) * 8 + q];
    }
    __syncthreads();
    int rowg0 = chunk_lo + half * 512;
    bool full = (rowg0 + 512) <= P_valid;
    for (int mtl = 0; mtl < 32; mtl++) {
      int rl = mtl * 16 + lr;
      bf16x8 a0 = *(bf16x8*)&smem[rl * 8 + swz];
      bf16x8 a1 = *(bf16x8*)&smem[rl * 8 + swz2];
      int rb = rowg0 + mtl * 16 + quad * 4;
#pragma unroll
      for (int tt = 0; tt < cMTW; tt++) {
        f32x4 acc = {0, 0, 0, 0};
        acc = mfma16(a0, bfr[tt][0], acc);
        acc = mfma16(a1, bfr[tt][1], acc);
        if (full) {
          cmax[tt] = fmaxf(cmax[tt], fmaxf(fmaxf(acc[0], acc[1]), fmaxf(acc[2], acc[3])));
        } else {
#pragma unroll
          for (int r = 0; r < 4; r++)
            cmax[tt] = fmaxf(cmax[tt], (rb + r) < P_valid ? acc[r] : -INFINITY);
        }
      }
    }
    __syncthreads();
  }
#pragma unroll
  for (int tt = 0; tt < cMTW; tt++) {
    float c = cmax[tt];
    c = fmaxf(c, __shfl_xor(c, 16));
    c = fmaxf(c, __shfl_xor(c, 32));
    if (quad == 0) msout[colbase + tt * 16 + lr] = c;
  }
}

// ---------------- top-KEEP selection (radix threshold; register-resident keys) ----------------
DEVI unsigned f2key(float f) {
  unsigned u = __float_as_uint(f);
  return (u & 0x80000000u) ? ~u : (u | 0x80000000u);
}

__device__ int scan_excl_1024(int v, int* lds, int* total) {
  int tid = threadIdx.x;
  lds[tid] = v;
  __syncthreads();
  for (int d = 1; d < 1024; d <<= 1) {
    int t = (tid >= d) ? lds[tid - d] : 0;
    __syncthreads();
    lds[tid] += t;
    __syncthreads();
  }
  *total = lds[1023];
  int e = lds[tid] - v;
  __syncthreads();
  return e;
}

__global__ __launch_bounds__(1024) void k_selneg(const float* msim, int* nsel, int* scal) {
  __shared__ int hist[256];
  __shared__ int suf[256];
  __shared__ int lds[1024];
  __shared__ unsigned sh_prefix;
  __shared__ int sh_rem;
  int b = blockIdx.x, tid = threadIdx.x;
  const float* ms0 = msim + ((size_t)b * 2 + 0) * cKC;
  const float* ms1 = msim + ((size_t)b * 2 + 1) * cKC;
  int P_valid = scal[b * 16 + 1], C_valid = scal[b * 16 + 2];
  int n_allowed = min(5 * P_valid, cKN);
  int nfin = (P_valid > 0) ? C_valid : 0;
  int KEEP = min(n_allowed, nfin);
  if (tid == 0) scal[b * 16 + 3] = KEEP;
  if (KEEP == 0) return;

  const int CH2 = cKC / 1024;  // 20
  int base = tid * CH2;
  unsigned keys[CH2];
#pragma unroll
  for (int e = 0; e < CH2; e++) {
    int c = base + e;
    keys[e] = (c < C_valid) ? f2key(fmaxf(ms0[c], ms1[c])) : 0u;
  }

  unsigned prefix = 0;
  int remaining = KEEP;
  for (int shift = 24; shift >= 0; shift -= 8) {
    if (tid < 256) hist[tid] = 0;
    __syncthreads();
#pragma unroll
    for (int e = 0; e < CH2; e++) {
      unsigned key = keys[e];
      if (shift == 24 || (key >> (shift + 8)) == prefix)
        atomicAdd(&hist[(key >> shift) & 255], 1);
    }
    __syncthreads();
    if (tid < 256) suf[tid] = hist[tid];
    __syncthreads();
    for (int d = 1; d < 256; d <<= 1) {
      int t = (tid < 256 && tid + d < 256) ? suf[tid + d] : 0;
      __syncthreads();
      if (tid < 256) suf[tid] += t;
      __syncthreads();
    }
    if (tid < 256) {
      int s = suf[tid];
      int sn = (tid < 255) ? suf[tid + 1] : 0;
      if (s >= remaining && sn < remaining) {
        sh_prefix = (prefix << 8) | (unsigned)tid;
        sh_rem = remaining - sn;
      }
    }
    __syncthreads();
    prefix = sh_prefix; remaining = sh_rem;
    __syncthreads();
  }
  unsigned T = prefix;

  int cntA = 0, cntT = 0;
#pragma unroll
  for (int e = 0; e < CH2; e++) {
    cntA += (keys[e] > T);
    cntT += (keys[e] == T);
  }
  int totA, totT;
  int offA = scan_excl_1024(cntA, lds, &totA);
  int offT = scan_excl_1024(cntT, lds, &totT);
  int* out = nsel + (size_t)b * cKN;
  int oa = offA, ot = offT;
  for (int e = 0; e < CH2; e++) {
    unsigned key = keys[e];
    if (key > T) { out[oa++] = base + e; }
    else if (key == T) { if (ot < remaining) out[totA + ot] = base + e; ot++; }
  }
}

// ---------------- gather negatives into G rows [cP, cP+cKN) (zero unused rows) ----------------
__global__ __launch_bounds__(256) void k_gather_neg(const __hip_bfloat16* cf, const int* nsel,
                                                    const int* scal, __hip_bfloat16* G) {
  int b = blockIdx.y;
  int KEEP = scal[b * 16 + 3];
  int t = blockIdx.x * 256 + threadIdx.x;
  int k = t >> 3, part = t & 7;
  if (k >= cKN) return;
  int4 val = {0, 0, 0, 0};
  if (k < KEEP) {
    int src = nsel[(size_t)b * cKN + k];
    val = *(const int4*)((const __bf16*)(cf + (size_t)b * cKC * cC) + (size_t)src * cC + part * 8);
  }
  *(int4*)((__bf16*)(G + (size_t)b * cNT * cC) + (size_t)(cP + k) * cC + part * 8) = val;
}

// ---------------- fused loss GEMM (64 rows/block, per-chunk E/L partials, B prefetch) ----------
__global__ __launch_bounds__(256) void k_loss(const __hip_bfloat16* G, const int* scal, float2* ELp) {
  __shared__ float sE[4][64];
  __shared__ float sL[4][64];
  int b = blockIdx.z, chunk = blockIdx.y;
  int P_valid = scal[b * 16 + 1];
  int KEEP = scal[b * 16 + 3];
  if (P_valid < 2) return;   // image unused by finalize
  int wave = threadIdx.x >> 6, lane = threadIdx.x & 63;
  int lr = lane & 15, quad = lane >> 4;
  int rowbase = blockIdx.x * 64;
  const __bf16* Gb = (const __bf16*)G + (size_t)b * cNT * cC;

  bf16x8 afr[4][2];
#pragma unroll
  for (int rt = 0; rt < 4; rt++) {
    const __bf16* src = Gb + (size_t)(rowbase + rt * 16 + lr) * cC + quad * 8;
    afr[rt][0] = *(const bf16x8*)src;
    afr[rt][1] = *(const bf16x8*)(src + 32);
  }
  float eacc[4][4] = {};
  float lacc[4][4] = {};
  int ct0 = chunk * cTPC;
  int ct_end = ct0 + cTPC;
  // prime the B pipeline
  const __bf16* bsrc0 = Gb + (size_t)((ct0 + wave) * 16 + lr) * cC + quad * 8;
  bf16x8 b0 = *(const bf16x8*)bsrc0;
  bf16x8 b1 = *(const bf16x8*)(bsrc0 + 32);
  for (int ct = ct0 + wave; ct < ct_end; ct += 4) {
    // prefetch next tile (clamped; loads are always address-safe within G)
    int ctn = min(ct + 4, ct_end - 1);
    const __bf16* nsrc = Gb + (size_t)(ctn * 16 + lr) * cC + quad * 8;
    bf16x8 nb0 = *(const bf16x8*)nsrc;
    bf16x8 nb1 = *(const bf16x8*)(nsrc + 32);
    int tb = ct * 16;
    bool is_pos = tb < cP;
    int vlimit = is_pos ? P_valid : (cP + KEEP);
    if (tb < vlimit) {
      bool all_valid = (tb + 16) <= vlimit;
      bool has_diag = is_pos && (tb >= rowbase) && (tb < rowbase + 64);
      f32x4 acc[4];
#pragma unroll
      for (int rt = 0; rt < 4; rt++) {
        f32x4 a = {0, 0, 0, 0};
        a = mfma16(afr[rt][0], b0, a);
        a = mfma16(afr[rt][1], b1, a);
        acc[rt] = a;
      }
      if (all_valid && !has_diag) {
        if (is_pos) {
#pragma unroll
          for (int rt = 0; rt < 4; rt++)
#pragma unroll
            for (int r = 0; r < 4; r++) {
              float logit = acc[rt][r] * cTEMP_INV;
              eacc[rt][r] += __expf(logit);
              lacc[rt][r] += logit;
            }
        } else {
#pragma unroll
          for (int rt = 0; rt < 4; rt++)
#pragma unroll
            for (int r = 0; r < 4; r++)
              eacc[rt][r] += __expf(acc[rt][r] * cTEMP_INV);
        }
      } else {
        bool colv = (tb + lr) < vlimit;
#pragma unroll
        for (int rt = 0; rt < 4; rt++) {
          int rb = rowbase + rt * 16 + quad * 4;
#pragma unroll
          for (int r = 0; r < 4; r++) {
            float logit = acc[rt][r] * cTEMP_INV;
            bool use = colv && !(has_diag && (tb + lr) == (rb + r));
            float e = __expf(logit);
            eacc[rt][r] += use ? e : 0.0f;
            if (is_pos) lacc[rt][r] += use ? logit : 0.0f;
          }
        }
      }
    }
    b0 = nb0; b1 = nb1;
  }
#pragma unroll
  for (int rt = 0; rt < 4; rt++) {
#pragma unroll
    for (int r = 0; r < 4; r++) {
      float e = eacc[rt][r], l = lacc[rt][r];
#pragma unroll
      for (int d = 1; d < 16; d <<= 1) {
        e += __shfl_xor(e, d);
        l += __shfl_xor(l, d);
      }
      if (lr == 0) {
        sE[wave][rt * 16 + quad * 4 + r] = e;
        sL[wave][rt * 16 + quad * 4 + r] = l;
      }
    }
  }
  __syncthreads();
  if (threadIdx.x < 64) {
    int row = rowbase + threadIdx.x;
    float E = sE[0][threadIdx.x] + sE[1][threadIdx.x] + sE[2][threadIdx.x] + sE[3][threadIdx.x];
    float L = sL[0][threadIdx.x] + sL[1][threadIdx.x] + sL[2][threadIdx.x] + sL[3][threadIdx.x];
    ELp[((size_t)chunk * cB + b) * cP + row] = make_float2(E, L);
  }
}

// ---------------- finalize: per-row loss, per-image mean, cross-image mean ----------------
__global__ __launch_bounds__(1024) void k_fin(const int* scal, const float2* ELp, float* out) {
  __shared__ float ssum[16];
  int tid = threadIdx.x;
  int b = tid >> 8, t = tid & 255;
  int Pv = scal[b * 16 + 1];
  float s = 0.f;
  if (Pv >= 2) {
    float inv = 1.0f / (float)(Pv - 1);
#pragma unroll
    for (int e = 0; e < 8; e++) {
      int row = t * 8 + e;
      if (row < Pv) {
        float E = 0.f, L = 0.f;
#pragma unroll
        for (int ch = 0; ch < cNCH; ch++) {
          float2 el = ELp[((size_t)ch * cB + b) * cP + row];
          E += el.x; L += el.y;
        }
        s += logf(E) - L * inv;
      }
    }
  }
#pragma unroll
  for (int d = 1; d < 64; d <<= 1) s += __shfl_xor(s, d);
  if ((tid & 63) == 0) ssum[tid >> 6] = s;
  __syncthreads();
  if (tid == 0) {
    float tot = 0.f;
    int cnt = 0;
    for (int bb = 0; bb < cB; bb++) {
      int P = scal[bb * 16 + 1];
      if (P >= 2) {
        float is = ssum[bb * 4] + ssum[bb * 4 + 1] + ssum[bb * 4 + 2] + ssum[bb * 4 + 3];
        tot += is / (float)P;
        cnt++;
      }
    }
    out[0] = tot / (float)(cnt > 0 ? cnt : 1);
  }
}

extern "C" void kernel_launch(void* const* d_in, const int* in_sizes, int n_in,
                              void* d_out, int out_size, void* d_ws, size_t ws_size,
                              hipStream_t stream) {
  const float* feat = (const float*)d_in[0];
  const int* labels = (const int*)d_in[1];
  char* ws = (char*)d_ws;
  unsigned char* fg  = (unsigned char*)(ws + off_fg);
  unsigned char* rim = (unsigned char*)(ws + off_rim);
  int* pidx = (int*)(ws + off_pidx);
  int* cidx = (int*)(ws + off_cidx);
  int* scal = (int*)(ws + off_scal);
  float2* ELp = (float2*)(ws + off_EL);
  float* msim = (float*)(ws + off_msim);
  int* nsel = (int*)(ws + off_nsel);
  __hip_bfloat16* G  = (__hip_bfloat16*)(ws + off_G);
  __hip_bfloat16* cf = (__hip_bfloat16*)(ws + off_cf);
  int* blkcnt = (int*)(ws + off_bcnt);
  float* out = (float*)d_out;

  k_mask<<<dim3(cNB, cB), 384, 0, stream>>>(labels, fg, rim, blkcnt);
  k_scatter<<<dim3(cNB, cB), 384, 0, stream>>>(fg, rim, blkcnt, scal, pidx, cidx);
  k_gather_norm<<<dim3(cP / 256 + cKC / 256, cB), 256, 0, stream>>>(feat, pidx, cidx, G, cf);
  k_mine<<<dim3(cKC / cMCB, 2, cB), 256, 0, stream>>>(G, cf, scal, msim);
  k_selneg<<<cB, 1024, 0, stream>>>(msim, nsel, scal);
  k_gather_neg<<<dim3(cKN * 8 / 256, cB), 256, 0, stream>>>(cf, nsel, scal, G);
  k_loss<<<dim3(cP / 64, cNCH, cB), 256, 0, stream>>>(G, scal, ELp);
  k_fin<<<1, 1024, 0, stream>>>(scal, ELp, out);
}